// Round 2
// baseline (561.266 us; speedup 1.0000x reference)
//
#include <hip/hip_runtime.h>

typedef __bf16 bf16;
typedef __bf16 bf16x2 __attribute__((ext_vector_type(2)));
typedef __bf16 bf16x4 __attribute__((ext_vector_type(4)));
typedef __bf16 bf16x8 __attribute__((ext_vector_type(8)));
typedef float  f32x4  __attribute__((ext_vector_type(4)));

#define MFMA16(a,b,c) __builtin_amdgcn_mfma_f32_16x16x32_bf16((a),(b),(c),0,0,0)

constexpr int Bn = 8, Sn = 4096, En = 2048, Ln = 64, Hn = 128;
constexpr int Mrows = Bn * Sn; // 32768

__device__ __forceinline__ void load_lds_16(const bf16* g, bf16* l) {
    __builtin_amdgcn_global_load_lds(
        (const __attribute__((address_space(1))) uint32_t*)g,
        (__attribute__((address_space(3))) uint32_t*)l, 16, 0, 0);
}

// ---------------- transpose + fp32->bf16: in[K][N] -> out[N][K] ----------------
__global__ __launch_bounds__(256) void transpose_cvt(const float* __restrict__ in,
                                                     bf16* __restrict__ out,
                                                     int K, int N) {
    int tid = blockIdx.x * 256 + threadIdx.x;
    if (tid >= K * N) return;
    int k = tid / N, n = tid - k * N;
    out[n * K + k] = (bf16)in[tid];
}

// ---------------- fused latent+q GEMM + k/v decompression epilogue ----------------
// C = x @ [w_dkv | w_q]; then k = latent@w_k, v^T = (latent@w_v)^T in the epilogue.
// 512 threads = 8 waves: wave = (mgrp 0..3) x (nhalf 0..1). BM=64, BN=192, BK=64.
__global__ __launch_bounds__(512) void gemm_xw(const float* __restrict__ x,
                                               const bf16* __restrict__ wT,    // [192][2048]
                                               const bf16* __restrict__ wkT,   // [128][64]
                                               const bf16* __restrict__ wvT,   // [128][64]
                                               float* __restrict__ latent_out, // [32768][64] fp32
                                               bf16* __restrict__ q_out,       // [32768][128] bf16
                                               bf16* __restrict__ k_out,       // [32768][128] bf16
                                               bf16* __restrict__ vT_out) {    // [8][128][4096] bf16
    __shared__ __align__(16) bf16 As[64 * 72];   // [row][k], +8 pad (reused as latent tile)
    __shared__ __align__(16) bf16 Bs[192 * 64];  // [n][k] XOR-swizzled, unpadded
    const int lane = threadIdx.x & 63;
    const int wave = threadIdx.x >> 6;           // 0..7
    const int col  = lane & 15, quad = lane >> 4;
    const int mgrp  = wave >> 1;                 // 0..3 : rows mgrp*16..+16
    const int nhalf = wave & 1;                  // 0..1 : nt 0..5 / 6..11
    const int mblock = blockIdx.x * 64;

    f32x4 acc[6];
#pragma unroll
    for (int t = 0; t < 6; ++t) acc[t] = (f32x4){0.f, 0.f, 0.f, 0.f};

    const int bsub = lane >> 3;             // 0..7 sub-row for B staging
    const int bkg0 = lane & 7;
    const int akc  = threadIdx.x & 15;      // 0..15 f32x4 column
    const int arow0 = threadIdx.x >> 4;     // 0..31

    for (int step = 0; step < 32; ++step) {
        __syncthreads();
        // --- B staging: 3 x global_load_lds per wave (8 rows x 128B each) ---
#pragma unroll
        for (int j = 0; j < 3; ++j) {
            int nr0 = wave * 24 + j * 8;
            int n = nr0 + bsub;
            int kgrp = bkg0 ^ bsub;            // XOR swizzle via global addr perm
            const bf16* g = wT + (size_t)n * En + step * 64 + kgrp * 8;
            load_lds_16(g, &Bs[nr0 * 64]);
        }
        // --- A staging: fp32 -> bf16 -> LDS, fully coalesced 16B/lane ---
#pragma unroll
        for (int p = 0; p < 2; ++p) {
            int row = p * 32 + arow0;
            f32x4 v = *(const f32x4*)(x + (size_t)(mblock + row) * En + step * 64 + akc * 4);
            bf16x4 c;
#pragma unroll
            for (int j = 0; j < 4; ++j) c[j] = (bf16)v[j];
            *(bf16x4*)(&As[row * 72 + akc * 4]) = c;
        }
        __syncthreads();
        // --- compute: 2 k-substeps x 6 n-tiles per wave ---
#pragma unroll
        for (int ks2 = 0; ks2 < 2; ++ks2) {
            bf16x8 a = *(const bf16x8*)(&As[(mgrp * 16 + col) * 72 + ks2 * 32 + quad * 8]);
#pragma unroll
            for (int t = 0; t < 6; ++t) {
                int n = nhalf * 96 + t * 16 + col;
                int sg = (ks2 * 4 + quad) ^ (col & 7);
                bf16x8 b = *(const bf16x8*)(&Bs[n * 64 + sg * 8]);
                acc[t] = MFMA16(a, b, acc[t]);
            }
        }
    }
    // ---- epilogue part 1: latent tile -> LDS (bf16), q/latent -> global ----
    __syncthreads();   // drain last compute's As reads before reuse
    if (nhalf == 0) {
#pragma unroll
        for (int t = 0; t < 4; ++t)
#pragma unroll
            for (int r = 0; r < 4; ++r)
                As[(mgrp * 16 + quad * 4 + r) * 72 + t * 16 + col] = (bf16)acc[t][r];
    }
#pragma unroll
    for (int t = 0; t < 6; ++t) {
        int gnt = nhalf * 6 + t;
#pragma unroll
        for (int r = 0; r < 4; ++r) {
            int row = mblock + mgrp * 16 + quad * 4 + r;
            if (gnt < 4) latent_out[(size_t)row * Ln + gnt * 16 + col] = acc[t][r];
            else         q_out[(size_t)row * Hn + (gnt - 4) * 16 + col] = (bf16)acc[t][r];
        }
    }
    __syncthreads();   // latent tile visible to all waves
    // ---- epilogue part 2: k/v decompression GEMM (K-dim = 64) ----
    // nhalf==0 waves -> k tile rows, nhalf==1 waves -> v tile rows (written transposed)
    const bf16* w2 = (nhalf == 0) ? wkT : wvT;
    f32x4 kv[8];
#pragma unroll
    for (int nt = 0; nt < 8; ++nt) kv[nt] = (f32x4){0.f, 0.f, 0.f, 0.f};
#pragma unroll
    for (int ks = 0; ks < 2; ++ks) {
        bf16x8 a = *(const bf16x8*)(&As[(mgrp * 16 + col) * 72 + ks * 32 + quad * 8]);
#pragma unroll
        for (int nt = 0; nt < 8; ++nt) {
            bf16x8 b = *(const bf16x8*)(w2 + (nt * 16 + col) * Ln + ks * 32 + quad * 8);
            kv[nt] = MFMA16(a, b, kv[nt]);
        }
    }
    if (nhalf == 0) {
#pragma unroll
        for (int nt = 0; nt < 8; ++nt)
#pragma unroll
            for (int r = 0; r < 4; ++r) {
                int row = mblock + mgrp * 16 + quad * 4 + r;
                k_out[(size_t)row * Hn + nt * 16 + col] = (bf16)kv[nt][r];
            }
    } else {
        int bb = mblock >> 12;
        int sbase = (mblock & 4095) + mgrp * 16 + quad * 4;
#pragma unroll
        for (int nt = 0; nt < 8; ++nt) {
            bf16x4 pv;
#pragma unroll
            for (int r = 0; r < 4; ++r) pv[r] = (bf16)kv[nt][r];
            *(bf16x4*)(vT_out + ((size_t)bb * Hn + nt * 16 + col) * Sn + sbase) = pv;
        }
    }
}

// ---------------- flash attention, causal, BQ=64 BK=64 D=128 ----------------
// 1D grid, globally work-descending: rank -> qtile = 63 - rank/8, bb = rank%8
// V arrives pre-transposed [b][d][s]: both K and V^T staged via global_load_lds DMA.
__global__ __launch_bounds__(256, 3) void mla_attn(const bf16* __restrict__ qg,
                                                   const bf16* __restrict__ kg,
                                                   const bf16* __restrict__ vtg,
                                                   float* __restrict__ outg) {
    __shared__ __align__(16) bf16 Ks[64 * 128];   // [key][d] XOR-swizzled, unpadded (DMA)
    __shared__ __align__(16) bf16 VtS[128 * 64];  // [d][key] XOR-swizzled, unpadded (DMA)
    __shared__ __align__(16) bf16 Pb[4][16][72];  // per-wave P, XOR-swizzled cols
    const int lane = threadIdx.x & 63;
    const int wave = threadIdx.x >> 6;
    const int col  = lane & 15, quad = lane >> 4;
    const int rank  = blockIdx.x;
    const int qtile = 63 - (rank >> 3);
    const int bb    = rank & 7;
    const int qbase = qtile * 64;
    const bf16* kb  = kg  + (size_t)bb * Sn * Hn;
    const bf16* vbT = vtg + (size_t)bb * Sn * Hn;   // [128][4096]

    bf16x8 qf[4];
    {
        const bf16* qrow = qg + ((size_t)bb * Sn + qbase + wave * 16 + col) * Hn;
#pragma unroll
        for (int ks = 0; ks < 4; ++ks)
            qf[ks] = *(const bf16x8*)(qrow + ks * 32 + quad * 8);
    }
    f32x4 o[8];
#pragma unroll
    for (int t = 0; t < 8; ++t) o[t] = (f32x4){0.f, 0.f, 0.f, 0.f};
    float m_run[4] = {-3.0e38f, -3.0e38f, -3.0e38f, -3.0e38f};
    float l_run[4] = {0.f, 0.f, 0.f, 0.f};
    const float scale = 0.08838834764831845f; // 1/sqrt(128)

    for (int kt = 0; kt <= qtile; ++kt) {
        __syncthreads();
        // --- K staging: global_load_lds, 4 instrs/wave, 4 keys each ---
#pragma unroll
        for (int ii = 0; ii < 4; ++ii) {
            int i = wave * 4 + ii;               // 0..15
            int key = 4 * i + (lane >> 4);
            int p = lane & 15;
            int g = (p & 8) | ((p & 7) ^ (key & 7));  // swizzle on global side
            const bf16* src = kb + (size_t)(kt * 64 + key) * Hn + g * 8;
            load_lds_16(src, Ks + i * 512);
        }
        // --- V^T staging: global_load_lds, 4 instrs/wave, 8 d-rows each ---
#pragma unroll
        for (int ii = 0; ii < 4; ++ii) {
            int i = wave * 4 + ii;               // 0..15 -> d rows i*8..+8
            int r = i * 8 + (lane >> 3);         // d 0..127
            int c = lane & 7;                    // dest 16B chunk in row
            int cs = c ^ (r & 7);                // source chunk (involution)
            const bf16* src = vbT + (size_t)r * Sn + kt * 64 + cs * 8;
            load_lds_16(src, VtS + i * 512);
        }
        __syncthreads();   // also drains the K/V DMA (vmcnt) per-wave

        // --- S = Q K^T (reads swizzled Ks) ---
        f32x4 sa[4];
#pragma unroll
        for (int nt = 0; nt < 4; ++nt) {
            sa[nt] = (f32x4){0.f, 0.f, 0.f, 0.f};
#pragma unroll
            for (int ks = 0; ks < 4; ++ks) {
                int key = nt * 16 + col;
                int g = ks * 4 + quad;
                int pos = (g & 8) | ((g & 7) ^ (col & 7));
                bf16x8 bfr = *(const bf16x8*)(Ks + key * 128 + pos * 8);
                sa[nt] = MFMA16(qf[ks], bfr, sa[nt]);
            }
        }
        float sc_[4][4];
        if (kt == qtile) {
#pragma unroll
            for (int nt = 0; nt < 4; ++nt)
#pragma unroll
                for (int r = 0; r < 4; ++r) {
                    float s = sa[nt][r] * scale;
                    if (nt * 16 + col > wave * 16 + quad * 4 + r) s = -1.0e30f;
                    sc_[nt][r] = s;
                }
        } else {
#pragma unroll
            for (int nt = 0; nt < 4; ++nt)
#pragma unroll
                for (int r = 0; r < 4; ++r) sc_[nt][r] = sa[nt][r] * scale;
        }
        // --- online softmax across quad's 16 lanes ---
        float mt[4];
#pragma unroll
        for (int r = 0; r < 4; ++r)
            mt[r] = fmaxf(fmaxf(sc_[0][r], sc_[1][r]), fmaxf(sc_[2][r], sc_[3][r]));
#pragma unroll
        for (int off = 1; off <= 8; off <<= 1)
#pragma unroll
            for (int r = 0; r < 4; ++r)
                mt[r] = fmaxf(mt[r], __shfl_xor(mt[r], off, 64));
        float alpha[4];
#pragma unroll
        for (int r = 0; r < 4; ++r) {
            float mn = fmaxf(m_run[r], mt[r]);
            alpha[r] = __expf(m_run[r] - mn);
            m_run[r] = mn;
        }
        float rs[4] = {0.f, 0.f, 0.f, 0.f};
#pragma unroll
        for (int nt = 0; nt < 4; ++nt)
#pragma unroll
            for (int r = 0; r < 4; ++r) {
                float p = __expf(sc_[nt][r] - m_run[r]);
                sc_[nt][r] = p;
                rs[r] += p;
            }
#pragma unroll
        for (int off = 1; off <= 8; off <<= 1)
#pragma unroll
            for (int r = 0; r < 4; ++r) rs[r] += __shfl_xor(rs[r], off, 64);
#pragma unroll
        for (int r = 0; r < 4; ++r) l_run[r] = l_run[r] * alpha[r] + rs[r];
#pragma unroll
        for (int t = 0; t < 8; ++t)
#pragma unroll
            for (int r = 0; r < 4; ++r) o[t][r] *= alpha[r];
        // --- P: C-layout -> LDS (swizzled, wave-private: NO barrier needed) ---
#pragma unroll
        for (int nt = 0; nt < 4; ++nt)
#pragma unroll
            for (int r = 0; r < 4; ++r)
                Pb[wave][quad * 4 + r][((nt ^ quad) & 3) * 16 + col] = (bf16)sc_[nt][r];
        // --- O += P V (reads swizzled VtS) ---
#pragma unroll
        for (int ks = 0; ks < 2; ++ks) {
            int pos = (ks * 32 + quad * 8) ^ ((col >> 2) * 16);
            bf16x8 pa = *(const bf16x8*)(&Pb[wave][col][pos]);
#pragma unroll
            for (int nt = 0; nt < 8; ++nt) {
                int row = nt * 16 + col;                   // d
                int g = (ks * 4 + quad) ^ (row & 7);       // swizzled 16B chunk
                bf16x8 bv = *(const bf16x8*)(VtS + row * 64 + g * 8);
                o[nt] = MFMA16(pa, bv, o[nt]);
            }
        }
    }
#pragma unroll
    for (int r = 0; r < 4; ++r) {
        float inv = 1.0f / l_run[r];
        int row = qbase + wave * 16 + quad * 4 + r;
        float* orow = outg + ((size_t)bb * Sn + row) * Hn;
#pragma unroll
        for (int t = 0; t < 8; ++t)
            orow[t * 16 + col] = o[t][r] * inv;
    }
}

extern "C" void kernel_launch(void* const* d_in, const int* in_sizes, int n_in,
                              void* d_out, int out_size, void* d_ws, size_t ws_size,
                              hipStream_t stream) {
    const float* x     = (const float*)d_in[0];
    const float* w_dkv = (const float*)d_in[1];
    const float* w_k   = (const float*)d_in[2];
    const float* w_v   = (const float*)d_in[3];
    const float* w_q   = (const float*)d_in[4];

    float* out        = (float*)d_out;                   // [8,4096,128] fp32
    float* latent_out = out + (size_t)Mrows * Hn;        // [8,4096,64]  fp32

    char* ws = (char*)d_ws;
    bf16* q_ws = (bf16*)(ws);                             // 8 MiB
    bf16* k_ws = (bf16*)(ws + (size_t)8  * 1024 * 1024);  // 8 MiB
    bf16* v_ws = (bf16*)(ws + (size_t)16 * 1024 * 1024);  // 8 MiB, V^T [8][128][4096]
    bf16* wT   = (bf16*)(ws + (size_t)24 * 1024 * 1024);  // [192][2048] bf16, 768 KiB
    bf16* wkT  = (bf16*)(ws + (size_t)24 * 1024 * 1024 + 768 * 1024);  // [128][64], 16 KiB
    bf16* wvT  = (bf16*)(ws + (size_t)24 * 1024 * 1024 + 784 * 1024);  // [128][64], 16 KiB

    transpose_cvt<<<(En * Ln + 255) / 256, 256, 0, stream>>>(w_dkv, wT, En, Ln);
    transpose_cvt<<<(En * Hn + 255) / 256, 256, 0, stream>>>(w_q, wT + (size_t)64 * En, En, Hn);
    transpose_cvt<<<(Ln * Hn + 255) / 256, 256, 0, stream>>>(w_k, wkT, Ln, Hn);
    transpose_cvt<<<(Ln * Hn + 255) / 256, 256, 0, stream>>>(w_v, wvT, Ln, Hn);
    gemm_xw<<<Mrows / 64, 512, 0, stream>>>(x, wT, wkT, wvT, latent_out, q_ws, k_ws, v_ws);
    mla_attn<<<Sn / 64 * Bn, 256, 0, stream>>>(q_ws, k_ws, v_ws, out);
}

// Round 3
// 533.202 us; speedup vs baseline: 1.0526x; 1.0526x over previous
//
#include <hip/hip_runtime.h>

typedef __bf16 bf16;
typedef __bf16 bf16x2 __attribute__((ext_vector_type(2)));
typedef __bf16 bf16x4 __attribute__((ext_vector_type(4)));
typedef __bf16 bf16x8 __attribute__((ext_vector_type(8)));
typedef float  f32x4  __attribute__((ext_vector_type(4)));

#define MFMA16(a,b,c) __builtin_amdgcn_mfma_f32_16x16x32_bf16((a),(b),(c),0,0,0)

constexpr int Bn = 8, Sn = 4096, En = 2048, Ln = 64, Hn = 128;
constexpr int Mrows = Bn * Sn; // 32768

__device__ __forceinline__ void load_lds_16(const bf16* g, bf16* l) {
    __builtin_amdgcn_global_load_lds(
        (const __attribute__((address_space(1))) uint32_t*)g,
        (__attribute__((address_space(3))) uint32_t*)l, 16, 0, 0);
}

// ---------------- transpose + fp32->bf16: in[K][N] -> out[N][K] ----------------
__global__ __launch_bounds__(256) void transpose_cvt(const float* __restrict__ in,
                                                     bf16* __restrict__ out,
                                                     int K, int N) {
    int tid = blockIdx.x * 256 + threadIdx.x;
    if (tid >= K * N) return;
    int k = tid / N, n = tid - k * N;
    out[n * K + k] = (bf16)in[tid];
}

// ---------------- fused latent+q GEMM + k/v decompression epilogue ----------------
// C = x @ [w_dkv | w_q]; then k = latent@w_k, v^T = (latent@w_v)^T in the epilogue.
// 512 threads = 8 waves: wave = (mgrp 0..3) x (nhalf 0..1). BM=64, BN=192, BK=64.
__global__ __launch_bounds__(512) void gemm_xw(const float* __restrict__ x,
                                               const bf16* __restrict__ wT,    // [192][2048]
                                               const bf16* __restrict__ wkT,   // [128][64]
                                               const bf16* __restrict__ wvT,   // [128][64]
                                               float* __restrict__ latent_out, // [32768][64] fp32
                                               bf16* __restrict__ q_out,       // [32768][128] bf16
                                               bf16* __restrict__ k_out,       // [32768][128] bf16
                                               bf16* __restrict__ vT_out) {    // [8][128][4096] bf16
    __shared__ __align__(16) bf16 As[64 * 72];   // [row][k], +8 pad (reused as latent tile)
    __shared__ __align__(16) bf16 Bs[192 * 64];  // [n][k] XOR-swizzled, unpadded
    const int lane = threadIdx.x & 63;
    const int wave = threadIdx.x >> 6;           // 0..7
    const int col  = lane & 15, quad = lane >> 4;
    const int mgrp  = wave >> 1;                 // 0..3 : rows mgrp*16..+16
    const int nhalf = wave & 1;                  // 0..1 : nt 0..5 / 6..11
    const int mblock = blockIdx.x * 64;

    f32x4 acc[6];
#pragma unroll
    for (int t = 0; t < 6; ++t) acc[t] = (f32x4){0.f, 0.f, 0.f, 0.f};

    const int bsub = lane >> 3;             // 0..7 sub-row for B staging
    const int bkg0 = lane & 7;
    const int akc  = threadIdx.x & 15;      // 0..15 f32x4 column
    const int arow0 = threadIdx.x >> 4;     // 0..31

    for (int step = 0; step < 32; ++step) {
        __syncthreads();
        // --- B staging: 3 x global_load_lds per wave (8 rows x 128B each) ---
#pragma unroll
        for (int j = 0; j < 3; ++j) {
            int nr0 = wave * 24 + j * 8;
            int n = nr0 + bsub;
            int kgrp = bkg0 ^ bsub;            // XOR swizzle via global addr perm
            const bf16* g = wT + (size_t)n * En + step * 64 + kgrp * 8;
            load_lds_16(g, &Bs[nr0 * 64]);
        }
        // --- A staging: fp32 -> bf16 -> LDS, fully coalesced 16B/lane ---
#pragma unroll
        for (int p = 0; p < 2; ++p) {
            int row = p * 32 + arow0;
            f32x4 v = *(const f32x4*)(x + (size_t)(mblock + row) * En + step * 64 + akc * 4);
            bf16x4 c;
#pragma unroll
            for (int j = 0; j < 4; ++j) c[j] = (bf16)v[j];
            *(bf16x4*)(&As[row * 72 + akc * 4]) = c;
        }
        __syncthreads();
        // --- compute: 2 k-substeps x 6 n-tiles per wave ---
#pragma unroll
        for (int ks2 = 0; ks2 < 2; ++ks2) {
            bf16x8 a = *(const bf16x8*)(&As[(mgrp * 16 + col) * 72 + ks2 * 32 + quad * 8]);
#pragma unroll
            for (int t = 0; t < 6; ++t) {
                int n = nhalf * 96 + t * 16 + col;
                int sg = (ks2 * 4 + quad) ^ (col & 7);
                bf16x8 b = *(const bf16x8*)(&Bs[n * 64 + sg * 8]);
                acc[t] = MFMA16(a, b, acc[t]);
            }
        }
    }
    // ---- epilogue part 1: latent tile -> LDS (bf16), q/latent -> global ----
    __syncthreads();   // drain last compute's As reads before reuse
    if (nhalf == 0) {
#pragma unroll
        for (int t = 0; t < 4; ++t)
#pragma unroll
            for (int r = 0; r < 4; ++r)
                As[(mgrp * 16 + quad * 4 + r) * 72 + t * 16 + col] = (bf16)acc[t][r];
    }
#pragma unroll
    for (int t = 0; t < 6; ++t) {
        int gnt = nhalf * 6 + t;
#pragma unroll
        for (int r = 0; r < 4; ++r) {
            int row = mblock + mgrp * 16 + quad * 4 + r;
            if (gnt < 4) latent_out[(size_t)row * Ln + gnt * 16 + col] = acc[t][r];
            else         q_out[(size_t)row * Hn + (gnt - 4) * 16 + col] = (bf16)acc[t][r];
        }
    }
    __syncthreads();   // latent tile visible to all waves
    // ---- epilogue part 2: k/v decompression GEMM (K-dim = 64) ----
    // nhalf==0 waves -> k tile rows, nhalf==1 waves -> v tile rows (written transposed)
    const bf16* w2 = (nhalf == 0) ? wkT : wvT;
    f32x4 kv[8];
#pragma unroll
    for (int nt = 0; nt < 8; ++nt) kv[nt] = (f32x4){0.f, 0.f, 0.f, 0.f};
#pragma unroll
    for (int ks = 0; ks < 2; ++ks) {
        bf16x8 a = *(const bf16x8*)(&As[(mgrp * 16 + col) * 72 + ks * 32 + quad * 8]);
#pragma unroll
        for (int nt = 0; nt < 8; ++nt) {
            bf16x8 b = *(const bf16x8*)(w2 + (nt * 16 + col) * Ln + ks * 32 + quad * 8);
            kv[nt] = MFMA16(a, b, kv[nt]);
        }
    }
    if (nhalf == 0) {
#pragma unroll
        for (int nt = 0; nt < 8; ++nt)
#pragma unroll
            for (int r = 0; r < 4; ++r) {
                int row = mblock + mgrp * 16 + quad * 4 + r;
                k_out[(size_t)row * Hn + nt * 16 + col] = (bf16)kv[nt][r];
            }
    } else {
        int bb = mblock >> 12;
        int sbase = (mblock & 4095) + mgrp * 16 + quad * 4;
#pragma unroll
        for (int nt = 0; nt < 8; ++nt) {
            bf16x4 pv;
#pragma unroll
            for (int r = 0; r < 4; ++r) pv[r] = (bf16)kv[nt][r];
            *(bf16x4*)(vT_out + ((size_t)bb * Hn + nt * 16 + col) * Sn + sbase) = pv;
        }
    }
}

// ---------------- flash attention, causal, BQ=64 BK=64 D=128 ----------------
// 1D grid, globally work-descending: rank -> qtile = 63 - rank/8, bb = rank%8
// Swapped QK^T (S^T = K Q^T): each lane owns ONE q-row (q=col) -> in-lane softmax.
__global__ __launch_bounds__(256, 3) void mla_attn(const bf16* __restrict__ qg,
                                                   const bf16* __restrict__ kg,
                                                   const bf16* __restrict__ vtg,
                                                   float* __restrict__ outg) {
    __shared__ __align__(16) bf16 Ks[64 * 128];   // [key][d] XOR-swizzled, unpadded (DMA)
    __shared__ __align__(16) bf16 VtS[128 * 64];  // [d][key] XOR-swizzled, unpadded (DMA)
    __shared__ __align__(16) bf16 Pb[4][16][72];  // per-wave P [q][key], XOR-swizzled cols
    const int lane = threadIdx.x & 63;
    const int wave = threadIdx.x >> 6;
    const int col  = lane & 15, quad = lane >> 4;
    const int rank  = blockIdx.x;
    const int qtile = 63 - (rank >> 3);
    const int bb    = rank & 7;
    const int qbase = qtile * 64;
    const bf16* kb  = kg  + (size_t)bb * Sn * Hn;
    const bf16* vbT = vtg + (size_t)bb * Sn * Hn;   // [128][4096]

    bf16x8 qf[4];
    {
        const bf16* qrow = qg + ((size_t)bb * Sn + qbase + wave * 16 + col) * Hn;
#pragma unroll
        for (int ks = 0; ks < 4; ++ks)
            qf[ks] = *(const bf16x8*)(qrow + ks * 32 + quad * 8);
    }
    f32x4 o[8];
#pragma unroll
    for (int t = 0; t < 8; ++t) o[t] = (f32x4){0.f, 0.f, 0.f, 0.f};
    float m_run = -3.0e38f;   // per-lane: q-row = qbase + wave*16 + col
    float l_run = 0.f;
    const float scale = 0.08838834764831845f; // 1/sqrt(128)
    const int qrow = wave * 16 + col;         // local q row (0..63)

    for (int kt = 0; kt <= qtile; ++kt) {
        __syncthreads();
        // --- K staging: global_load_lds, 4 instrs/wave, 4 keys each ---
#pragma unroll
        for (int ii = 0; ii < 4; ++ii) {
            int i = wave * 4 + ii;               // 0..15
            int key = 4 * i + (lane >> 4);
            int p = lane & 15;
            int g = (p & 8) | ((p & 7) ^ (key & 7));  // swizzle on global side
            const bf16* src = kb + (size_t)(kt * 64 + key) * Hn + g * 8;
            load_lds_16(src, Ks + i * 512);
        }
        // --- V^T staging: global_load_lds, 4 instrs/wave, 8 d-rows each ---
#pragma unroll
        for (int ii = 0; ii < 4; ++ii) {
            int i = wave * 4 + ii;               // 0..15 -> d rows i*8..+8
            int r = i * 8 + (lane >> 3);         // d 0..127
            int c = lane & 7;                    // dest 16B chunk in row
            int cs = c ^ (r & 7);                // source chunk (involution)
            const bf16* src = vbT + (size_t)r * Sn + kt * 64 + cs * 8;
            load_lds_16(src, VtS + i * 512);
        }
        __syncthreads();   // also drains the K/V DMA (vmcnt) per-wave

        // --- S^T = K Q^T (swapped operands; reads swizzled Ks as A-frag) ---
        f32x4 sa[4];
#pragma unroll
        for (int nt = 0; nt < 4; ++nt) {
            sa[nt] = (f32x4){0.f, 0.f, 0.f, 0.f};
#pragma unroll
            for (int ks = 0; ks < 4; ++ks) {
                int key = nt * 16 + col;
                int g = ks * 4 + quad;
                int pos = (g & 8) | ((g & 7) ^ (col & 7));
                bf16x8 kfr = *(const bf16x8*)(Ks + key * 128 + pos * 8);
                sa[nt] = MFMA16(kfr, qf[ks], sa[nt]);   // D[key][q]
            }
        }
        // lane holds S[key_local = nt*16 + quad*4 + r][q = qrow]
        float p_[4][4];
        if (kt == qtile) {
#pragma unroll
            for (int nt = 0; nt < 4; ++nt)
#pragma unroll
                for (int r = 0; r < 4; ++r) {
                    float s = sa[nt][r] * scale;
                    if (nt * 16 + quad * 4 + r > qrow) s = -1.0e30f;
                    p_[nt][r] = s;
                }
        } else {
#pragma unroll
            for (int nt = 0; nt < 4; ++nt)
#pragma unroll
                for (int r = 0; r < 4; ++r) p_[nt][r] = sa[nt][r] * scale;
        }
        // --- online softmax: in-lane 16-max + 2 shfl (quads hold the 64 keys) ---
        float mt = p_[0][0];
#pragma unroll
        for (int nt = 0; nt < 4; ++nt)
#pragma unroll
            for (int r = 0; r < 4; ++r) mt = fmaxf(mt, p_[nt][r]);
        mt = fmaxf(mt, __shfl_xor(mt, 16, 64));
        mt = fmaxf(mt, __shfl_xor(mt, 32, 64));
        float mn = fmaxf(m_run, mt);
        float alpha = __expf(m_run - mn);
        m_run = mn;
        float rs = 0.f;
#pragma unroll
        for (int nt = 0; nt < 4; ++nt)
#pragma unroll
            for (int r = 0; r < 4; ++r) {
                float p = __expf(p_[nt][r] - mn);
                p_[nt][r] = p;
                rs += p;
            }
        rs += __shfl_xor(rs, 16, 64);
        rs += __shfl_xor(rs, 32, 64);
        l_run = l_run * alpha + rs;
        // --- broadcast alpha to PV accumulator layout (q = quad*4+r) ---
        float al[4];
#pragma unroll
        for (int r = 0; r < 4; ++r) al[r] = __shfl(alpha, quad * 4 + r, 64);
#pragma unroll
        for (int t = 0; t < 8; ++t)
#pragma unroll
            for (int r = 0; r < 4; ++r) o[t][r] *= al[r];
        // --- P -> LDS: 4 x ds_write_b64, group-XOR matches pa read (wave-private) ---
#pragma unroll
        for (int nt = 0; nt < 4; ++nt) {
            bf16x4 pv;
#pragma unroll
            for (int r = 0; r < 4; ++r) pv[r] = (bf16)p_[nt][r];
            *(bf16x4*)(&Pb[wave][col][((nt ^ (col >> 2)) & 3) * 16 + quad * 4]) = pv;
        }
        // --- O += P V (reads swizzled VtS; pa read unchanged) ---
#pragma unroll
        for (int ks = 0; ks < 2; ++ks) {
            int pos = (ks * 32 + quad * 8) ^ ((col >> 2) * 16);
            bf16x8 pa = *(const bf16x8*)(&Pb[wave][col][pos]);
#pragma unroll
            for (int nt = 0; nt < 8; ++nt) {
                int row = nt * 16 + col;                   // d
                int g = (ks * 4 + quad) ^ (row & 7);       // swizzled 16B chunk
                bf16x8 bv = *(const bf16x8*)(VtS + row * 64 + g * 8);
                o[nt] = MFMA16(pa, bv, o[nt]);
            }
        }
    }
    // --- final: bring l into PV layout (q = quad*4+r), normalize, store ---
    float lr[4];
#pragma unroll
    for (int r = 0; r < 4; ++r) lr[r] = __shfl(l_run, quad * 4 + r, 64);
#pragma unroll
    for (int r = 0; r < 4; ++r) {
        float inv = 1.0f / lr[r];
        int row = qbase + wave * 16 + quad * 4 + r;
        float* orow = outg + ((size_t)bb * Sn + row) * Hn;
#pragma unroll
        for (int t = 0; t < 8; ++t)
            orow[t * 16 + col] = o[t][r] * inv;
    }
}

extern "C" void kernel_launch(void* const* d_in, const int* in_sizes, int n_in,
                              void* d_out, int out_size, void* d_ws, size_t ws_size,
                              hipStream_t stream) {
    const float* x     = (const float*)d_in[0];
    const float* w_dkv = (const float*)d_in[1];
    const float* w_k   = (const float*)d_in[2];
    const float* w_v   = (const float*)d_in[3];
    const float* w_q   = (const float*)d_in[4];

    float* out        = (float*)d_out;                   // [8,4096,128] fp32
    float* latent_out = out + (size_t)Mrows * Hn;        // [8,4096,64]  fp32

    char* ws = (char*)d_ws;
    bf16* q_ws = (bf16*)(ws);                             // 8 MiB
    bf16* k_ws = (bf16*)(ws + (size_t)8  * 1024 * 1024);  // 8 MiB
    bf16* v_ws = (bf16*)(ws + (size_t)16 * 1024 * 1024);  // 8 MiB, V^T [8][128][4096]
    bf16* wT   = (bf16*)(ws + (size_t)24 * 1024 * 1024);  // [192][2048] bf16, 768 KiB
    bf16* wkT  = (bf16*)(ws + (size_t)24 * 1024 * 1024 + 768 * 1024);  // [128][64], 16 KiB
    bf16* wvT  = (bf16*)(ws + (size_t)24 * 1024 * 1024 + 784 * 1024);  // [128][64], 16 KiB

    transpose_cvt<<<(En * Ln + 255) / 256, 256, 0, stream>>>(w_dkv, wT, En, Ln);
    transpose_cvt<<<(En * Hn + 255) / 256, 256, 0, stream>>>(w_q, wT + (size_t)64 * En, En, Hn);
    transpose_cvt<<<(Ln * Hn + 255) / 256, 256, 0, stream>>>(w_k, wkT, Ln, Hn);
    transpose_cvt<<<(Ln * Hn + 255) / 256, 256, 0, stream>>>(w_v, wvT, Ln, Hn);
    gemm_xw<<<Mrows / 64, 512, 0, stream>>>(x, wT, wkT, wvT, latent_out, q_ws, k_ws, v_ws);
    mla_attn<<<Sn / 64 * Bn, 256, 0, stream>>>(q_ws, k_ws, v_ws, out);
}

// Round 5
// 510.694 us; speedup vs baseline: 1.0990x; 1.0441x over previous
//
#include <hip/hip_runtime.h>

typedef __bf16 bf16;
typedef __bf16 bf16x2 __attribute__((ext_vector_type(2)));
typedef __bf16 bf16x4 __attribute__((ext_vector_type(4)));
typedef __bf16 bf16x8 __attribute__((ext_vector_type(8)));
typedef float  f32x4  __attribute__((ext_vector_type(4)));

#define MFMA16(a,b,c) __builtin_amdgcn_mfma_f32_16x16x32_bf16((a),(b),(c),0,0,0)

constexpr int Bn = 8, Sn = 4096, En = 2048, Ln = 64, Hn = 128;
constexpr int Mrows = Bn * Sn; // 32768

__device__ __forceinline__ void load_lds_16(const bf16* g, bf16* l) {
    __builtin_amdgcn_global_load_lds(
        (const __attribute__((address_space(1))) uint32_t*)g,
        (__attribute__((address_space(3))) uint32_t*)l, 16, 0, 0);
}

// ---------------- transpose + fp32->bf16: in[K][N] -> out[N][K] ----------------
__global__ __launch_bounds__(256) void transpose_cvt(const float* __restrict__ in,
                                                     bf16* __restrict__ out,
                                                     int K, int N) {
    int tid = blockIdx.x * 256 + threadIdx.x;
    if (tid >= K * N) return;
    int k = tid / N, n = tid - k * N;
    out[n * K + k] = (bf16)in[tid];
}

// ---------------- fused latent+q GEMM + k/v decompression epilogue ----------------
// C = x @ [w_dkv | w_q]; then k = latent@w_k, v^T = (latent@w_v)^T in the epilogue.
// 512 threads = 8 waves: wave = (mgrp 0..3) x (nhalf 0..1). BM=64, BN=192, BK=64.
__global__ __launch_bounds__(512) void gemm_xw(const float* __restrict__ x,
                                               const bf16* __restrict__ wT,    // [192][2048]
                                               const bf16* __restrict__ wkT,   // [128][64]
                                               const bf16* __restrict__ wvT,   // [128][64]
                                               float* __restrict__ latent_out, // [32768][64] fp32
                                               bf16* __restrict__ q_out,       // [32768][128] bf16
                                               bf16* __restrict__ k_out,       // [32768][128] bf16
                                               bf16* __restrict__ vT_out) {    // [8][128][4096] bf16
    __shared__ __align__(16) bf16 As[64 * 72];   // [row][k], +8 pad (reused as latent tile)
    __shared__ __align__(16) bf16 Bs[192 * 64];  // [n][k] XOR-swizzled, unpadded
    const int lane = threadIdx.x & 63;
    const int wave = threadIdx.x >> 6;           // 0..7
    const int col  = lane & 15, quad = lane >> 4;
    const int mgrp  = wave >> 1;                 // 0..3 : rows mgrp*16..+16
    const int nhalf = wave & 1;                  // 0..1 : nt 0..5 / 6..11
    const int mblock = blockIdx.x * 64;

    f32x4 acc[6];
#pragma unroll
    for (int t = 0; t < 6; ++t) acc[t] = (f32x4){0.f, 0.f, 0.f, 0.f};

    const int bsub = lane >> 3;             // 0..7 sub-row for B staging
    const int bkg0 = lane & 7;
    const int akc  = threadIdx.x & 15;      // 0..15 f32x4 column
    const int arow0 = threadIdx.x >> 4;     // 0..31

    for (int step = 0; step < 32; ++step) {
        __syncthreads();
        // --- B staging: 3 x global_load_lds per wave (8 rows x 128B each) ---
#pragma unroll
        for (int j = 0; j < 3; ++j) {
            int nr0 = wave * 24 + j * 8;
            int n = nr0 + bsub;
            int kgrp = bkg0 ^ bsub;            // XOR swizzle via global addr perm
            const bf16* g = wT + (size_t)n * En + step * 64 + kgrp * 8;
            load_lds_16(g, &Bs[nr0 * 64]);
        }
        // --- A staging: fp32 -> bf16 -> LDS, fully coalesced 16B/lane ---
#pragma unroll
        for (int p = 0; p < 2; ++p) {
            int row = p * 32 + arow0;
            f32x4 v = *(const f32x4*)(x + (size_t)(mblock + row) * En + step * 64 + akc * 4);
            bf16x4 c;
#pragma unroll
            for (int j = 0; j < 4; ++j) c[j] = (bf16)v[j];
            *(bf16x4*)(&As[row * 72 + akc * 4]) = c;
        }
        __syncthreads();
        // --- compute: 2 k-substeps x 6 n-tiles per wave ---
#pragma unroll
        for (int ks2 = 0; ks2 < 2; ++ks2) {
            bf16x8 a = *(const bf16x8*)(&As[(mgrp * 16 + col) * 72 + ks2 * 32 + quad * 8]);
#pragma unroll
            for (int t = 0; t < 6; ++t) {
                int n = nhalf * 96 + t * 16 + col;
                int sg = (ks2 * 4 + quad) ^ (col & 7);
                bf16x8 b = *(const bf16x8*)(&Bs[n * 64 + sg * 8]);
                acc[t] = MFMA16(a, b, acc[t]);
            }
        }
    }
    // ---- epilogue part 1: latent tile -> LDS (bf16), q/latent -> global ----
    __syncthreads();   // drain last compute's As reads before reuse
    if (nhalf == 0) {
#pragma unroll
        for (int t = 0; t < 4; ++t)
#pragma unroll
            for (int r = 0; r < 4; ++r)
                As[(mgrp * 16 + quad * 4 + r) * 72 + t * 16 + col] = (bf16)acc[t][r];
    }
#pragma unroll
    for (int t = 0; t < 6; ++t) {
        int gnt = nhalf * 6 + t;
#pragma unroll
        for (int r = 0; r < 4; ++r) {
            int row = mblock + mgrp * 16 + quad * 4 + r;
            if (gnt < 4) latent_out[(size_t)row * Ln + gnt * 16 + col] = acc[t][r];
            else         q_out[(size_t)row * Hn + (gnt - 4) * 16 + col] = (bf16)acc[t][r];
        }
    }
    __syncthreads();   // latent tile visible to all waves
    // ---- epilogue part 2: k/v decompression GEMM (K-dim = 64) ----
    // nhalf==0 waves -> k tile rows, nhalf==1 waves -> v tile rows (written transposed)
    const bf16* w2 = (nhalf == 0) ? wkT : wvT;
    f32x4 kv[8];
#pragma unroll
    for (int nt = 0; nt < 8; ++nt) kv[nt] = (f32x4){0.f, 0.f, 0.f, 0.f};
#pragma unroll
    for (int ks = 0; ks < 2; ++ks) {
        bf16x8 a = *(const bf16x8*)(&As[(mgrp * 16 + col) * 72 + ks * 32 + quad * 8]);
#pragma unroll
        for (int nt = 0; nt < 8; ++nt) {
            bf16x8 b = *(const bf16x8*)(w2 + (nt * 16 + col) * Ln + ks * 32 + quad * 8);
            kv[nt] = MFMA16(a, b, kv[nt]);
        }
    }
    if (nhalf == 0) {
#pragma unroll
        for (int nt = 0; nt < 8; ++nt)
#pragma unroll
            for (int r = 0; r < 4; ++r) {
                int row = mblock + mgrp * 16 + quad * 4 + r;
                k_out[(size_t)row * Hn + nt * 16 + col] = (bf16)kv[nt][r];
            }
    } else {
        int bb = mblock >> 12;
        int sbase = (mblock & 4095) + mgrp * 16 + quad * 4;
#pragma unroll
        for (int nt = 0; nt < 8; ++nt) {
            bf16x4 pv;
#pragma unroll
            for (int r = 0; r < 4; ++r) pv[r] = (bf16)kv[nt][r];
            *(bf16x4*)(vT_out + ((size_t)bb * Hn + nt * 16 + col) * Sn + sbase) = pv;
        }
    }
}

// ---------------- flash attention, causal, BQ=64 BK=64 D=128 ----------------
// 1D grid, globally work-descending: rank -> qtile = 63 - rank/8, bb = rank%8
// Swapped QK^T (S^T = K Q^T): each lane owns ONE q-row -> in-lane softmax.
// K/V double-buffered in LDS; DMA prefetch with counted vmcnt(8) across raw
// s_barrier (T3+T4): next tile's 8 loads stay in flight through compute.
__global__ __launch_bounds__(256, 2) void mla_attn(const bf16* __restrict__ qg,
                                                   const bf16* __restrict__ kg,
                                                   const bf16* __restrict__ vtg,
                                                   float* __restrict__ outg) {
    __shared__ __align__(16) bf16 Ks[2][64 * 128];   // [key][d] XOR-swizzled (DMA)
    __shared__ __align__(16) bf16 VtS[2][128 * 64];  // [d][key] XOR-swizzled (DMA)
    __shared__ __align__(16) bf16 Pb[4][16][72];     // per-wave P [q][key], XOR cols
    const int lane = threadIdx.x & 63;
    const int wave = threadIdx.x >> 6;
    const int col  = lane & 15, quad = lane >> 4;
    const int rank  = blockIdx.x;
    const int qtile = 63 - (rank >> 3);
    const int bb    = rank & 7;
    const int qbase = qtile * 64;
    const bf16* kb  = kg  + (size_t)bb * Sn * Hn;
    const bf16* vbT = vtg + (size_t)bb * Sn * Hn;   // [128][4096]

    bf16x8 qf[4];
    {
        const bf16* qrow = qg + ((size_t)bb * Sn + qbase + wave * 16 + col) * Hn;
#pragma unroll
        for (int ks = 0; ks < 4; ++ks)
            qf[ks] = *(const bf16x8*)(qrow + ks * 32 + quad * 8);
    }
    f32x4 o[8];
#pragma unroll
    for (int t = 0; t < 8; ++t) o[t] = (f32x4){0.f, 0.f, 0.f, 0.f};
    float m_run = -3.0e38f;   // per-lane: q-row = qbase + wave*16 + col
    float l_run = 0.f;
    const float scale = 0.08838834764831845f; // 1/sqrt(128)
    const int qrow = wave * 16 + col;         // local q row (0..63)

    // stage tile kt_ into buffer buf: 8 DMA instrs per wave (4 K + 4 V^T)
    auto stage = [&](int buf, int kt_) {
#pragma unroll
        for (int ii = 0; ii < 4; ++ii) {
            int i = wave * 4 + ii;               // 0..15
            int key = 4 * i + (lane >> 4);
            int p = lane & 15;
            int g = (p & 8) | ((p & 7) ^ (key & 7));  // swizzle on global side
            load_lds_16(kb + (size_t)(kt_ * 64 + key) * Hn + g * 8, &Ks[buf][i * 512]);
        }
#pragma unroll
        for (int ii = 0; ii < 4; ++ii) {
            int i = wave * 4 + ii;               // 0..15 -> d rows i*8..+8
            int r = i * 8 + (lane >> 3);         // d 0..127
            int cs = (lane & 7) ^ (r & 7);       // source chunk (involution)
            load_lds_16(vbT + (size_t)r * Sn + kt_ * 64 + cs * 8, &VtS[buf][i * 512]);
        }
    };

    stage(0, 0);
    for (int kt = 0; kt <= qtile; ++kt) {
        const int cur = kt & 1;
        if (kt < qtile) {
            stage(cur ^ 1, kt + 1);              // prefetch next tile (8 loads in flight)
            asm volatile("s_waitcnt vmcnt(8)" ::: "memory");   // current tile's loads done
        } else {
            asm volatile("s_waitcnt vmcnt(0)" ::: "memory");
        }
        __builtin_amdgcn_s_barrier();            // all waves' DMA for tile kt landed
        __builtin_amdgcn_sched_barrier(0);
        const bf16* KsC = Ks[cur];
        const bf16* VtC = VtS[cur];

        // --- S^T = K Q^T (swapped operands; reads swizzled Ks as A-frag) ---
        f32x4 sa[4];
#pragma unroll
        for (int nt = 0; nt < 4; ++nt) {
            sa[nt] = (f32x4){0.f, 0.f, 0.f, 0.f};
#pragma unroll
            for (int ks = 0; ks < 4; ++ks) {
                int key = nt * 16 + col;
                int g = ks * 4 + quad;
                int pos = (g & 8) | ((g & 7) ^ (col & 7));
                bf16x8 kfr = *(const bf16x8*)(KsC + key * 128 + pos * 8);
                sa[nt] = MFMA16(kfr, qf[ks], sa[nt]);   // D[key][q]
            }
        }
        // lane holds S[key_local = nt*16 + quad*4 + r][q = qrow]
        float p_[4][4];
        if (kt == qtile) {
#pragma unroll
            for (int nt = 0; nt < 4; ++nt)
#pragma unroll
                for (int r = 0; r < 4; ++r) {
                    float s = sa[nt][r] * scale;
                    if (nt * 16 + quad * 4 + r > qrow) s = -1.0e30f;
                    p_[nt][r] = s;
                }
        } else {
#pragma unroll
            for (int nt = 0; nt < 4; ++nt)
#pragma unroll
                for (int r = 0; r < 4; ++r) p_[nt][r] = sa[nt][r] * scale;
        }
        // --- online softmax: in-lane 16-max + 2 shfl (quads hold the 64 keys) ---
        float mt = p_[0][0];
#pragma unroll
        for (int nt = 0; nt < 4; ++nt)
#pragma unroll
            for (int r = 0; r < 4; ++r) mt = fmaxf(mt, p_[nt][r]);
        mt = fmaxf(mt, __shfl_xor(mt, 16, 64));
        mt = fmaxf(mt, __shfl_xor(mt, 32, 64));
        float mn = fmaxf(m_run, mt);
        float alpha = __expf(m_run - mn);
        m_run = mn;
        float rs = 0.f;
#pragma unroll
        for (int nt = 0; nt < 4; ++nt)
#pragma unroll
            for (int r = 0; r < 4; ++r) {
                float p = __expf(p_[nt][r] - mn);
                p_[nt][r] = p;
                rs += p;
            }
        rs += __shfl_xor(rs, 16, 64);
        rs += __shfl_xor(rs, 32, 64);
        l_run = l_run * alpha + rs;
        // --- broadcast alpha to PV accumulator layout (q = quad*4+r) ---
        float al[4];
#pragma unroll
        for (int r = 0; r < 4; ++r) al[r] = __shfl(alpha, quad * 4 + r, 64);
#pragma unroll
        for (int t = 0; t < 8; ++t)
#pragma unroll
            for (int r = 0; r < 4; ++r) o[t][r] *= al[r];
        // --- P -> LDS: 4 x ds_write_b64, group-XOR matches pa read (wave-private) ---
#pragma unroll
        for (int nt = 0; nt < 4; ++nt) {
            bf16x4 pv;
#pragma unroll
            for (int r = 0; r < 4; ++r) pv[r] = (bf16)p_[nt][r];
            *(bf16x4*)(&Pb[wave][col][((nt ^ (col >> 2)) & 3) * 16 + quad * 4]) = pv;
        }
        // --- O += P V (reads swizzled VtS; pa read unchanged) ---
#pragma unroll
        for (int ks = 0; ks < 2; ++ks) {
            int pos = (ks * 32 + quad * 8) ^ ((col >> 2) * 16);
            bf16x8 pa = *(const bf16x8*)(&Pb[wave][col][pos]);
#pragma unroll
            for (int nt = 0; nt < 8; ++nt) {
                int row = nt * 16 + col;                   // d
                int g = (ks * 4 + quad) ^ (row & 7);       // swizzled 16B chunk
                bf16x8 bv = *(const bf16x8*)(VtC + row * 64 + g * 8);
                o[nt] = MFMA16(pa, bv, o[nt]);
            }
        }
        __builtin_amdgcn_sched_barrier(0);
        __builtin_amdgcn_s_barrier();   // all reads of buf[cur^1]'s predecessor done
    }
    // --- final: bring l into PV layout (q = quad*4+r), normalize, store ---
    float lr[4];
#pragma unroll
    for (int r = 0; r < 4; ++r) lr[r] = __shfl(l_run, quad * 4 + r, 64);
#pragma unroll
    for (int r = 0; r < 4; ++r) {
        float inv = 1.0f / lr[r];
        int row = qbase + wave * 16 + quad * 4 + r;
        float* orow = outg + ((size_t)bb * Sn + row) * Hn;
#pragma unroll
        for (int t = 0; t < 8; ++t)
            orow[t * 16 + col] = o[t][r] * inv;
    }
}

extern "C" void kernel_launch(void* const* d_in, const int* in_sizes, int n_in,
                              void* d_out, int out_size, void* d_ws, size_t ws_size,
                              hipStream_t stream) {
    const float* x     = (const float*)d_in[0];
    const float* w_dkv = (const float*)d_in[1];
    const float* w_k   = (const float*)d_in[2];
    const float* w_v   = (const float*)d_in[3];
    const float* w_q   = (const float*)d_in[4];

    float* out        = (float*)d_out;                   // [8,4096,128] fp32
    float* latent_out = out + (size_t)Mrows * Hn;        // [8,4096,64]  fp32

    char* ws = (char*)d_ws;
    bf16* q_ws = (bf16*)(ws);                             // 8 MiB
    bf16* k_ws = (bf16*)(ws + (size_t)8  * 1024 * 1024);  // 8 MiB
    bf16* v_ws = (bf16*)(ws + (size_t)16 * 1024 * 1024);  // 8 MiB, V^T [8][128][4096]
    bf16* wT   = (bf16*)(ws + (size_t)24 * 1024 * 1024);  // [192][2048] bf16, 768 KiB
    bf16* wkT  = (bf16*)(ws + (size_t)24 * 1024 * 1024 + 768 * 1024);  // [128][64], 16 KiB
    bf16* wvT  = (bf16*)(ws + (size_t)24 * 1024 * 1024 + 784 * 1024);  // [128][64], 16 KiB

    transpose_cvt<<<(En * Ln + 255) / 256, 256, 0, stream>>>(w_dkv, wT, En, Ln);
    transpose_cvt<<<(En * Hn + 255) / 256, 256, 0, stream>>>(w_q, wT + (size_t)64 * En, En, Hn);
    transpose_cvt<<<(Ln * Hn + 255) / 256, 256, 0, stream>>>(w_k, wkT, Ln, Hn);
    transpose_cvt<<<(Ln * Hn + 255) / 256, 256, 0, stream>>>(w_v, wvT, Ln, Hn);
    gemm_xw<<<Mrows / 64, 512, 0, stream>>>(x, wT, wkT, wvT, latent_out, q_ws, k_ws, v_ws);
    mla_attn<<<Sn / 64 * Bn, 256, 0, stream>>>(q_ws, k_ws, v_ws, out);
}